// Round 12
// baseline (267.460 us; speedup 1.0000x reference)
//
#include <hip/hip_runtime.h>

// 2-layer LSTM (B=4096, T=256, I=38, H1=50, H2=15) + FC on last step.
// R12: R10's swapped-operand MFMA + in-register update, split into
// 2 independent blocks/CU: SB=8 seqs, 256 thr (4 waves), grid=512.
// Wave wv owns tiles {wv,wv+4,wv+8,wv+12} (+tile16 on wv3); 4 updates/lane.
// One barrier/step; 2-step-ahead x prefetch; L2 one step behind L1.

typedef _Float16 f16x8 __attribute__((ext_vector_type(8)));
typedef float    f32x4 __attribute__((ext_vector_type(4)));

#if __has_builtin(__builtin_amdgcn_exp2f)
#define DEV_EXP2(x) __builtin_amdgcn_exp2f(x)
#else
#define DEV_EXP2(x) exp2f(x)
#endif
#if __has_builtin(__builtin_amdgcn_rcpf)
#define DEV_RCP(x) __builtin_amdgcn_rcpf(x)
#else
#define DEV_RCP(x) (1.0f/(x))
#endif

#define I1 38
#define H1 50
#define H2 15
#define NC 14
#define TT 256
#define SB 8
// A-row (f16): [x:0..37 | h1:38..87 | h2:88..102 | zero:..127 | pad..135]
#define XS 136
#define NTH 256
#define L2E 2.885390081777927f
#define L1E 1.442695040888963f

#define MF(A,B,C) __builtin_amdgcn_mfma_f32_16x16x32_f16((A),(B),(C),0,0,0)

__device__ __forceinline__ float sigm(float v)  { return DEV_RCP(1.f + DEV_EXP2(-L1E * v)); }
__device__ __forceinline__ float tanh_f(float v){ return 1.f - 2.f * DEV_RCP(1.f + DEV_EXP2(L2E * v)); }

__launch_bounds__(NTH, 2)
__global__ void lstm2_fused(const float* __restrict__ x,
                            const float* __restrict__ w_ih1, const float* __restrict__ w_hh1,
                            const float* __restrict__ b_ih1, const float* __restrict__ b_hh1,
                            const float* __restrict__ w_ih2, const float* __restrict__ w_hh2,
                            const float* __restrict__ b_ih2, const float* __restrict__ b_hh2,
                            const float* __restrict__ w_fc, const float* __restrict__ b_fc,
                            float* __restrict__ out)
{
  __shared__ __align__(16) _Float16 bufA[2][SB][XS];

  const int tid  = threadIdx.x;
  const int wv   = tid >> 6;          // 0..3
  const int lane = tid & 63;
  const int lm   = lane & 15;         // D col (seq; 8..15 duplicate 0..7)
  const int lk   = lane >> 4;         // k chunk / local unit within quad-tile
  const int arow = lm & 7;            // A-read seq row
  const int blk  = blockIdx.x;
  const float* xblk = x + (size_t)blk * SB * TT * I1;

  // ---- zero A buffers ----
  for (int i = tid; i < 2*SB*XS; i += NTH) ((_Float16*)bufA)[i] = (_Float16)0.f;

  // ---- weight element fetch (unified-k, gate-row r = 4u+g) ----
  auto welem = [&](bool il1, bool valid, int u, int g, int k) -> _Float16 {
    float w = 0.f;
    if (valid) {
      if (il1) {
        if (k < I1)                w = w_ih1[(g*H1 + u)*I1 + k];
        else if (k < I1 + H1)      w = w_hh1[(g*H1 + u)*H1 + (k - I1)];
      } else {
        if (k >= I1 && k < I1+H1)             w = w_ih2[(g*H2 + u)*H1 + (k - I1)];
        else if (k >= I1+H1 && k < I1+H1+H2)  w = w_hh2[(g*H2 + u)*H2 + (k - I1 - H1)];
      }
    }
    return (_Float16)w;
  };

  // ---- per-slot fragment geometry: tile ts = wv + 4*s ----
  // rows r = ts*16 + lm; quad q = r>>2 (= unit id), g = r&3
  int   uF[4]; bool il1F[4];
  #pragma unroll
  for (int s = 0; s < 4; ++s) {
    const int r = (wv + 4*s)*16 + lm;
    const int q = r >> 2;
    il1F[s] = (q < H1);
    uF[s]   = il1F[s] ? q : (q - H1);
  }
  const int gF = lm & 3;        // gate within quad, same for all slots
  const bool w16 = (wv == 3);
  const bool c16 = w16 && (lm < 4);    // tile16 rows: unit 64 (L2 u14), g = lm

  // W fragments: slots 0-2 need ks 0..2; slot 3 ks 0..3 (ks0 rows are zero
  // for pure-L2 tiles by welem's range conditions); tile16 ks 1..3.
  f16x8 W0[3], W1[3], W2[3], W3[4], W16[3];
  #pragma unroll
  for (int ks = 0; ks < 3; ++ks) {
    f16x8 v0, v1v, v2;
    #pragma unroll
    for (int e = 0; e < 8; ++e) {
      const int k = ks*32 + lk*8 + e;
      v0[e]  = welem(il1F[0], true, uF[0], gF, k);
      v1v[e] = welem(il1F[1], true, uF[1], gF, k);
      v2[e]  = welem(il1F[2], true, uF[2], gF, k);
    }
    W0[ks] = v0; W1[ks] = v1v; W2[ks] = v2;
  }
  #pragma unroll
  for (int ks = 0; ks < 4; ++ks) {
    f16x8 v;
    #pragma unroll
    for (int e = 0; e < 8; ++e) v[e] = welem(il1F[3], true, uF[3], gF, ks*32 + lk*8 + e);
    W3[ks] = v;
  }
  #pragma unroll
  for (int j = 0; j < 3; ++j) {
    f16x8 v;
    #pragma unroll
    for (int e = 0; e < 8; ++e) v[e] = welem(false, c16, 14, lm & 3, (j+1)*32 + lk*8 + e);
    W16[j] = v;
  }

  // ---- update geometry: lane (lm,lk), slot s -> unit 4*(wv+4s)+lk, seq lm ----
  int dU[4]; bool il1U[4];
  float sb[4][4];
  #pragma unroll
  for (int s = 0; s < 4; ++s) {
    const int u = 4*(wv + 4*s) + lk;
    il1U[s] = (u < H1);
    const int ur = il1U[s] ? u : (u - H1);
    dU[s] = il1U[s] ? (38 + u) : (88 + ur);
    #pragma unroll
    for (int m = 0; m < 4; ++m)
      sb[s][m] = il1U[s] ? (b_ih1[m*H1 + u] + b_hh1[m*H1 + u])
                         : (b_ih2[m*H2 + ur] + b_hh2[m*H2 + ur]);
  }
  const bool hasC = w16 && (lk == 0);
  float sbC[4];
  #pragma unroll
  for (int m = 0; m < 4; ++m) sbC[m] = b_ih2[m*H2 + 14] + b_hh2[m*H2 + 14];

  // ---- x staging: 304 f32/step over 256 threads ----
  const int e1x = tid + 256;
  const bool v1 = (tid < SB*I1 - 256);       // tid < 48
  const int s0 = tid / I1,  k0 = tid % I1;
  const int s1 = e1x / I1,  k1 = e1x % I1;
  const int gb0 = s0*TT*I1 + k0, gb1 = v1 ? (s1*TT*I1 + k1) : 0;
  const int lb0 = s0*XS + k0,    lb1 = v1 ? (s1*XS + k1) : 0;

  __syncthreads();              // zeros visible
  {                             // stage x(0)
    _Float16* b0 = &bufA[0][0][0];
    b0[lb0] = (_Float16)xblk[gb0];
    if (v1) b0[lb1] = (_Float16)xblk[gb1];
  }
  float xA0 = 0.f, xA1 = 0.f, xB0 = 0.f, xB1 = 0.f;
  xA0 = xblk[gb0 + I1];                     // prefetch x(1)
  if (v1) xA1 = xblk[gb1 + I1];
  __syncthreads();

  float cS[4] = {0.f, 0.f, 0.f, 0.f};
  float cC = 0.f;

  // in-register LSTM update for one (unit, seq=lm) pair
  auto upd = [&](const f32x4& acc, float& c, int dcol, bool up, _Float16* nxt) {
    if (up && lm < SB) {
      float ig = sigm(acc[0]), fg = sigm(acc[1]);
      float gg = tanh_f(acc[2]), og = sigm(acc[3]);
      c = fg * c + ig * gg;
      nxt[lm*XS + dcol] = (_Float16)(og * tanh_f(c));
    }
  };

#define STEP(T, XC0, XC1, XN0, XN1) do {                                        \
    _Float16* cur = &bufA[(T) & 1][0][0];                                       \
    _Float16* nxt = &bufA[((T) & 1) ^ 1][0][0];                                 \
    if ((T) + 2 < TT) {                                                         \
      const int go = ((T) + 2) * I1;                                            \
      XN0 = xblk[gb0 + go];                                                     \
      if (v1) XN1 = xblk[gb1 + go];                                             \
    }                                                                           \
    f16x8 a0 = *(const f16x8*)(cur + arow*XS +      lk*8);                      \
    f16x8 a1 = *(const f16x8*)(cur + arow*XS + 32 + lk*8);                      \
    f16x8 a2 = *(const f16x8*)(cur + arow*XS + 64 + lk*8);                      \
    f16x8 a3 = *(const f16x8*)(cur + arow*XS + 96 + lk*8);                      \
    {                                                                           \
      f32x4 acc = (f32x4){sb[0][0], sb[0][1], sb[0][2], sb[0][3]};              \
      acc = MF(W0[0], a0, acc); acc = MF(W0[1], a1, acc);                       \
      acc = MF(W0[2], a2, acc);                                                 \
      upd(acc, cS[0], dU[0], (T) < TT, nxt);                                    \
    }                                                                           \
    {                                                                           \
      f32x4 acc = (f32x4){sb[1][0], sb[1][1], sb[1][2], sb[1][3]};              \
      acc = MF(W1[0], a0, acc); acc = MF(W1[1], a1, acc);                       \
      acc = MF(W1[2], a2, acc);                                                 \
      upd(acc, cS[1], dU[1], (T) < TT, nxt);                                    \
    }                                                                           \
    {                                                                           \
      f32x4 acc = (f32x4){sb[2][0], sb[2][1], sb[2][2], sb[2][3]};              \
      acc = MF(W2[0], a0, acc); acc = MF(W2[1], a1, acc);                       \
      acc = MF(W2[2], a2, acc);                                                 \
      upd(acc, cS[2], dU[2], (T) < TT, nxt);                                    \
    }                                                                           \
    {                                                                           \
      f32x4 acc = (f32x4){sb[3][0], sb[3][1], sb[3][2], sb[3][3]};              \
      acc = MF(W3[0], a0, acc); acc = MF(W3[1], a1, acc);                       \
      acc = MF(W3[2], a2, acc); acc = MF(W3[3], a3, acc);                       \
      upd(acc, cS[3], dU[3], il1U[3] ? ((T) < TT) : ((T) >= 1), nxt);           \
    }                                                                           \
    if (w16) {                                                                  \
      f32x4 acc = (f32x4){sbC[0], sbC[1], sbC[2], sbC[3]};                      \
      acc = MF(W16[0], a1, acc); acc = MF(W16[1], a2, acc);                     \
      acc = MF(W16[2], a3, acc);                                                \
      if (hasC && (T) >= 1) {                                                   \
        float ig = sigm(acc[0]), fg = sigm(acc[1]);                             \
        float gg = tanh_f(acc[2]), og = sigm(acc[3]);                           \
        cC = fg*cC + ig*gg;                                                     \
        if (lm < SB) nxt[lm*XS + 102] = (_Float16)(og * tanh_f(cC));            \
      }                                                                         \
    }                                                                           \
    if ((T) + 1 < TT) {                                                         \
      nxt[lb0] = (_Float16)XC0;                                                 \
      if (v1) nxt[lb1] = (_Float16)XC1;                                         \
    }                                                                           \
    __syncthreads();                                                            \
  } while (0)

  int t = 0;
  for (;;) {
    STEP(t, xA0, xA1, xB0, xB1);
    if (++t > TT) break;
    STEP(t, xB0, xB1, xA0, xA1);
    if (++t > TT) break;
  }
#undef STEP

  // ---- FC on h2(255) (bufA[1], cols 88..102) ----
  if (tid < SB*NC) {
    int s = tid / NC, n = tid % NC;
    float acc = b_fc[n];
    #pragma unroll
    for (int u = 0; u < H2; ++u)
      acc += (float)bufA[1][s][88 + u] * w_fc[n*H2 + u];
    out[((size_t)blk*SB + s)*NC + n] = acc;
  }
}

extern "C" void kernel_launch(void* const* d_in, const int* in_sizes, int n_in,
                              void* d_out, int out_size, void* d_ws, size_t ws_size,
                              hipStream_t stream) {
  (void)n_in; (void)d_ws; (void)ws_size; (void)out_size;
  const float* x     = (const float*)d_in[0];
  const float* w_ih1 = (const float*)d_in[1];
  const float* w_hh1 = (const float*)d_in[2];
  const float* b_ih1 = (const float*)d_in[3];
  const float* b_hh1 = (const float*)d_in[4];
  const float* w_ih2 = (const float*)d_in[5];
  const float* w_hh2 = (const float*)d_in[6];
  const float* b_ih2 = (const float*)d_in[7];
  const float* b_hh2 = (const float*)d_in[8];
  const float* w_fc  = (const float*)d_in[9];
  const float* b_fc  = (const float*)d_in[10];
  float* out = (float*)d_out;

  const int B = in_sizes[0] / (TT * I1);   // 4096
  dim3 grid(B / SB), block(NTH);
  lstm2_fused<<<grid, block, 0, stream>>>(x, w_ih1, w_hh1, b_ih1, b_hh1,
                                          w_ih2, w_hh2, b_ih2, b_hh2,
                                          w_fc, b_fc, out);
}

// Round 13
// 198.685 us; speedup vs baseline: 1.3462x; 1.3462x over previous
//
#include <hip/hip_runtime.h>

// 2-layer LSTM (B=4096, T=256, I=38, H1=50, H2=15) + FC on last step.
// R13: 1024 thr / 16 waves, SB=16, grid=256 (1 block/CU, 4 waves/SIMD).
// Wave w owns tile w (16 gate-rows = 4 units); wave 15 also tile16 (L2 u14).
// Swapped-operand MFMA -> in-register LSTM update (1 pair/lane, dense).
// x staged via 8-step padded LDS window (stride 328), filled with coalesced
// float2 loads once per 8 steps; A-fragments read x straight from the window.
// k-layout: [x:0..37|pad:38,39|h1:40..89|h2:90..104|zeros:105..127].
// One barrier per step. L2 pipelined one step behind L1.

typedef _Float16 f16x8 __attribute__((ext_vector_type(8)));
typedef _Float16 f16x2 __attribute__((ext_vector_type(2)));
typedef float    f32x4 __attribute__((ext_vector_type(4)));

#if __has_builtin(__builtin_amdgcn_exp2f)
#define DEV_EXP2(x) __builtin_amdgcn_exp2f(x)
#else
#define DEV_EXP2(x) exp2f(x)
#endif
#if __has_builtin(__builtin_amdgcn_rcpf)
#define DEV_RCP(x) __builtin_amdgcn_rcpf(x)
#else
#define DEV_RCP(x) (1.0f/(x))
#endif

#define I1 38
#define H1 50
#define H2 15
#define NC 14
#define TT 256
#define SB 16
#define NTH 1024
#define WSR 328                  // window per-seq stride (f16): 8*40 + 8 pad
#define HS  88                   // h per-seq stride (f16)
#define WIN_SZ (2*SB*WSR)        // 10496 f16
#define H_OFF  WIN_SZ
#define SMEM_N (WIN_SZ + 2*SB*HS)  // 13312 f16
#define L2E 2.885390081777927f
#define L1E 1.442695040888963f

#define MF(A,B,C) __builtin_amdgcn_mfma_f32_16x16x32_f16((A),(B),(C),0,0,0)

__device__ __forceinline__ float sigm(float v)  { return DEV_RCP(1.f + DEV_EXP2(-L1E * v)); }
__device__ __forceinline__ float tanh_f(float v){ return 1.f - 2.f * DEV_RCP(1.f + DEV_EXP2(L2E * v)); }

__launch_bounds__(NTH)
__global__ void lstm2_fused(const float* __restrict__ x,
                            const float* __restrict__ w_ih1, const float* __restrict__ w_hh1,
                            const float* __restrict__ b_ih1, const float* __restrict__ b_hh1,
                            const float* __restrict__ w_ih2, const float* __restrict__ w_hh2,
                            const float* __restrict__ b_ih2, const float* __restrict__ b_hh2,
                            const float* __restrict__ w_fc, const float* __restrict__ b_fc,
                            float* __restrict__ out)
{
  __shared__ __align__(16) _Float16 smem[SMEM_N];

  const int tid  = threadIdx.x;
  const int wv   = tid >> 6;          // 0..15
  const int lane = tid & 63;
  const int lm   = lane & 15;         // seq (D col); W-fragment row
  const int lkq  = lane >> 4;         // k chunk / local unit
  const int blk  = blockIdx.x;
  const float* xblk = x + (size_t)blk * SB * TT * I1;

  // ---- zero all LDS (window pads + h regions must be 0) ----
  for (int i = tid; i < SMEM_N/2; i += NTH) ((int*)smem)[i] = 0;

  // ---- weight element fetch; k-layout x<38 | h1 40..89 | h2 90..104 ----
  auto welem = [&](bool il1, bool valid, int u, int g, int k) -> _Float16 {
    float w = 0.f;
    if (valid) {
      if (il1) {
        if (k < I1)                 w = w_ih1[(g*H1 + u)*I1 + k];
        else if (k >= 40 && k < 90) w = w_hh1[(g*H1 + u)*H1 + (k - 40)];
      } else {
        if (k >= 40 && k < 90)        w = w_ih2[(g*H2 + u)*H1 + (k - 40)];
        else if (k >= 90 && k < 105)  w = w_hh2[(g*H2 + u)*H2 + (k - 90)];
      }
    }
    return (_Float16)w;
  };

  // ---- W fragments: tile wv, row lm -> unit-quad 4*wv + (lm>>2), gate lm&3 ----
  const int quadW = 4*wv + (lm >> 2);
  const int gW = lm & 3;
  const bool il1W = (quadW < H1);
  const int uW = il1W ? quadW : (quadW - H1);

  f16x8 W[4];
  #pragma unroll
  for (int ks = 0; ks < 4; ++ks) {
    f16x8 v;
    #pragma unroll
    for (int e = 0; e < 8; ++e) v[e] = welem(il1W, true, uW, gW, ks*32 + lkq*8 + e);
    W[ks] = v;
  }
  const bool w16 = (wv == 15);
  const bool c16 = w16 && (lm < 4);         // tile16 rows: unit 64 (L2 u14), g=lm
  f16x8 W16[3];
  #pragma unroll
  for (int j = 0; j < 3; ++j) {
    f16x8 v;
    #pragma unroll
    for (int e = 0; e < 8; ++e) v[e] = welem(false, c16, 14, lm & 3, (j+1)*32 + lkq*8 + e);
    W16[j] = v;
  }

  // ---- update geometry: lane (lm,lkq) owns (unit 4*wv+lkq, seq lm) ----
  const int uU = 4*wv + lkq;                // 0..63; h col = uU
  const bool il1U = (uU < H1);
  float sb[4], sbC[4];
  #pragma unroll
  for (int m = 0; m < 4; ++m) {
    sb[m] = il1U ? (b_ih1[m*H1 + uU] + b_hh1[m*H1 + uU])
                 : (b_ih2[m*H2 + (uU - H1)] + b_hh2[m*H2 + (uU - H1)]);
    sbC[m] = b_ih2[m*H2 + 14] + b_hh2[m*H2 + 14];
  }

  __syncthreads();              // zeros visible before window fill

  // ---- window fill: 16 seq x 8 steps x 19 float2, coalesced ----
  auto fill = [&](int t0, int wb) {
    #pragma unroll
    for (int it = 0; it < 3; ++it) {
      int e = it*NTH + tid;
      if (e < SB*152) {                       // 2432
        int s = e / 152, r = e % 152, tw = r / 19, q = r % 19;
        const float2 v = *(const float2*)(xblk + (size_t)s*TT*I1 + (t0 + tw)*I1 + 2*q);
        f16x2 h; h[0] = (_Float16)v.x; h[1] = (_Float16)v.y;
        *(f16x2*)&smem[wb*(SB*WSR) + s*WSR + tw*40 + 2*q] = h;
      }
    }
  };
  fill(0, 0);
  fill(8, 1);
  __syncthreads();

  float cU = 0.f, cC = 0.f;

  for (int t = 0; t <= TT; ++t) {
    const int par = t & 1;
    const _Float16* curh = smem + H_OFF + par*(SB*HS);
    _Float16*       nxth = smem + H_OFF + (par ^ 1)*(SB*HS);
    const _Float16* wint = smem + ((t >> 3) & 1)*(SB*WSR) + (t & 7)*40;

    // refill: window (t/8)+1 into its buffer (last read ended at t-1's barrier)
    if ((t & 7) == 0 && t >= 8 && t + 8 < TT)
      fill(t + 8, ((t >> 3) + 1) & 1);

    // A fragments (zero-init where conditionally loaded — no undef)
    f16x8 a0 = (f16x8)(_Float16)0.f;
    if (wv <= 12) a0 = *(const f16x8*)(wint + lm*WSR + lkq*8);
    const _Float16* p1 = lkq ? (curh + lm*HS + (lkq*8 - 8))
                             : (wint + lm*WSR + 32);
    f16x8 a1 = *(const f16x8*)p1;
    f16x8 a2 = *(const f16x8*)(curh + lm*HS + 24 + lkq*8);
    f16x8 a3 = (f16x8)(_Float16)0.f;
    if (wv >= 12) a3 = *(const f16x8*)(curh + lm*HS + 56 + lkq*8);

    // ---- main tile MFMA + in-register update ----
    {
      f32x4 acc = (f32x4){sb[0], sb[1], sb[2], sb[3]};
      if (wv <= 12) acc = MF(W[0], a0, acc);
      acc = MF(W[1], a1, acc);
      acc = MF(W[2], a2, acc);
      if (wv >= 12) acc = MF(W[3], a3, acc);
      const bool up = il1U ? (t < TT) : (t >= 1);
      if (up) {
        float ig = sigm(acc[0]), fg = sigm(acc[1]);
        float gg = tanh_f(acc[2]), og = sigm(acc[3]);
        cU = fg*cU + ig*gg;
        nxth[lm*HS + uU] = (_Float16)(og * tanh_f(cU));
      }
    }
    // ---- tile16 on wave 15 ----
    if (w16) {
      f32x4 acc = (f32x4){sbC[0], sbC[1], sbC[2], sbC[3]};
      acc = MF(W16[0], a1, acc);
      acc = MF(W16[1], a2, acc);
      acc = MF(W16[2], a3, acc);
      if (lkq == 0 && t >= 1) {
        float ig = sigm(acc[0]), fg = sigm(acc[1]);
        float gg = tanh_f(acc[2]), og = sigm(acc[3]);
        cC = fg*cC + ig*gg;
        nxth[lm*HS + 64] = (_Float16)(og * tanh_f(cC));
      }
    }

    __syncthreads();
  }

  // ---- FC on h2(255): s_h buffer 1, cols 50..64 ----
  if (tid < SB*NC) {
    int s = tid / NC, n = tid % NC;
    float acc = b_fc[n];
    const _Float16* h2p = smem + H_OFF + (SB*HS) + s*HS + H1;
    #pragma unroll
    for (int u = 0; u < H2; ++u)
      acc += (float)h2p[u] * w_fc[n*H2 + u];
    out[((size_t)blk*SB + s)*NC + n] = acc;
  }
}

extern "C" void kernel_launch(void* const* d_in, const int* in_sizes, int n_in,
                              void* d_out, int out_size, void* d_ws, size_t ws_size,
                              hipStream_t stream) {
  (void)n_in; (void)d_ws; (void)ws_size; (void)out_size;
  const float* x     = (const float*)d_in[0];
  const float* w_ih1 = (const float*)d_in[1];
  const float* w_hh1 = (const float*)d_in[2];
  const float* b_ih1 = (const float*)d_in[3];
  const float* b_hh1 = (const float*)d_in[4];
  const float* w_ih2 = (const float*)d_in[5];
  const float* w_hh2 = (const float*)d_in[6];
  const float* b_ih2 = (const float*)d_in[7];
  const float* b_hh2 = (const float*)d_in[8];
  const float* w_fc  = (const float*)d_in[9];
  const float* b_fc  = (const float*)d_in[10];
  float* out = (float*)d_out;

  const int B = in_sizes[0] / (TT * I1);   // 4096
  dim3 grid(B / SB), block(NTH);
  lstm2_fused<<<grid, block, 0, stream>>>(x, w_ih1, w_hh1, b_ih1, b_hh1,
                                          w_ih2, w_hh2, b_ih2, b_hh2,
                                          w_fc, b_fc, out);
}

// Round 15
// 196.576 us; speedup vs baseline: 1.3606x; 1.0107x over previous
//
#include <hip/hip_runtime.h>

// 2-layer LSTM (B=4096, T=256, I=38, H1=50, H2=15) + FC on last step.
// R15: SB=8, 256 thr (4 waves), grid=512 -> 2 independent blocks/CU.
// Swapped-operand MFMA (tiles {wv,wv+4,wv+8,wv+12}+tile16 on wv3). Since
// A-rows 8-15 duplicate rows 0-7 (arow=lm&7), D cols 8-15 equal cols 0-7,
// so the slot-pair merge is a plain per-lane SELECT (no cross-lane ops):
// lanes lm<8 update slot 2p's unit, lanes lm>=8 update slot 2p+1's unit
// -> every lane runs a dense in-register LSTM update (2/lane).
// One barrier/step; 2-step x prefetch; L2 one step behind L1.

typedef _Float16 f16x8 __attribute__((ext_vector_type(8)));
typedef float    f32x4 __attribute__((ext_vector_type(4)));

#if __has_builtin(__builtin_amdgcn_exp2f)
#define DEV_EXP2(x) __builtin_amdgcn_exp2f(x)
#else
#define DEV_EXP2(x) exp2f(x)
#endif
#if __has_builtin(__builtin_amdgcn_rcpf)
#define DEV_RCP(x) __builtin_amdgcn_rcpf(x)
#else
#define DEV_RCP(x) (1.0f/(x))
#endif

#define I1 38
#define H1 50
#define H2 15
#define NC 14
#define TT 256
#define SB 8
// A-row (f16): [x:0..37 | h1:38..87 | h2:88..102 | zero:..127 | pad..135]
#define XS 136
#define NTH 256
#define L2E 2.885390081777927f
#define L1E 1.442695040888963f

#define MF(A,B,C) __builtin_amdgcn_mfma_f32_16x16x32_f16((A),(B),(C),0,0,0)

__device__ __forceinline__ float sigm(float v)  { return DEV_RCP(1.f + DEV_EXP2(-L1E * v)); }
__device__ __forceinline__ float tanh_f(float v){ return 1.f - 2.f * DEV_RCP(1.f + DEV_EXP2(L2E * v)); }

__launch_bounds__(NTH, 2)
__global__ void lstm2_fused(const float* __restrict__ x,
                            const float* __restrict__ w_ih1, const float* __restrict__ w_hh1,
                            const float* __restrict__ b_ih1, const float* __restrict__ b_hh1,
                            const float* __restrict__ w_ih2, const float* __restrict__ w_hh2,
                            const float* __restrict__ b_ih2, const float* __restrict__ b_hh2,
                            const float* __restrict__ w_fc, const float* __restrict__ b_fc,
                            float* __restrict__ out)
{
  __shared__ __align__(16) _Float16 bufA[2][SB][XS];

  const int tid  = threadIdx.x;
  const int wv   = tid >> 6;          // 0..3
  const int lane = tid & 63;
  const int lm   = lane & 15;
  const int lk   = lane >> 4;
  const int arow = lm & 7;            // seq for A-reads and updates
  const int blk  = blockIdx.x;
  const float* xblk = x + (size_t)blk * SB * TT * I1;

  // ---- zero A buffers ----
  for (int i = tid; i < 2*SB*XS; i += NTH) ((_Float16*)bufA)[i] = (_Float16)0.f;

  // ---- weight element fetch (unified-k, gate-row r = 4u+g) ----
  auto welem = [&](bool il1, bool valid, int u, int g, int k) -> _Float16 {
    float w = 0.f;
    if (valid) {
      if (il1) {
        if (k < I1)                w = w_ih1[(g*H1 + u)*I1 + k];
        else if (k < I1 + H1)      w = w_hh1[(g*H1 + u)*H1 + (k - I1)];
      } else {
        if (k >= I1 && k < I1+H1)             w = w_ih2[(g*H2 + u)*H1 + (k - I1)];
        else if (k >= I1+H1 && k < I1+H1+H2)  w = w_hh2[(g*H2 + u)*H2 + (k - I1 - H1)];
      }
    }
    return (_Float16)w;
  };

  // ---- W fragments: slot s = tile wv+4s, row lm -> quad (wv+4s)*4+(lm>>2), g=lm&3 ----
  int   uF[4]; bool il1F[4];
  #pragma unroll
  for (int s = 0; s < 4; ++s) {
    const int q = (wv + 4*s)*4 + (lm >> 2);
    il1F[s] = (q < H1);
    uF[s]   = il1F[s] ? q : (q - H1);
  }
  const int gF = lm & 3;
  const bool w16 = (wv == 3);
  const bool c16 = w16 && (lm < 4);    // tile16 rows: unit 64 (L2 u14), g=lm

  f16x8 W0[3], W1[3], W2[3], W3[4], W16[3];
  #pragma unroll
  for (int ks = 0; ks < 3; ++ks) {
    f16x8 v0, v1v, v2;
    #pragma unroll
    for (int e = 0; e < 8; ++e) {
      const int k = ks*32 + lk*8 + e;
      v0[e]  = welem(il1F[0], true, uF[0], gF, k);
      v1v[e] = welem(il1F[1], true, uF[1], gF, k);
      v2[e]  = welem(il1F[2], true, uF[2], gF, k);
    }
    W0[ks] = v0; W1[ks] = v1v; W2[ks] = v2;
  }
  #pragma unroll
  for (int ks = 0; ks < 4; ++ks) {
    f16x8 v;
    #pragma unroll
    for (int e = 0; e < 8; ++e) v[e] = welem(il1F[3], true, uF[3], gF, ks*32 + lk*8 + e);
    W3[ks] = v;
  }
  #pragma unroll
  for (int j = 0; j < 3; ++j) {
    f16x8 v;
    #pragma unroll
    for (int e = 0; e < 8; ++e) v[e] = welem(false, c16, 14, lm & 3, (j+1)*32 + lk*8 + e);
    W16[j] = v;
  }

  // ---- biases (C-init, per slot: gate m, unit 4*(wv+4s)+lk) ----
  float sb[4][4], sbC[4];
  #pragma unroll
  for (int s = 0; s < 4; ++s) {
    const int u = 4*(wv + 4*s) + lk;
    const bool il1 = (u < H1);
    const int ur = il1 ? u : (u - H1);
    #pragma unroll
    for (int m = 0; m < 4; ++m)
      sb[s][m] = il1 ? (b_ih1[m*H1 + u] + b_hh1[m*H1 + u])
                     : (b_ih2[m*H2 + ur] + b_hh2[m*H2 + ur]);
  }
  #pragma unroll
  for (int m = 0; m < 4; ++m) sbC[m] = b_ih2[m*H2 + 14] + b_hh2[m*H2 + 14];

  // ---- dense-update lane geometry per slot-pair p = {slot 2p, slot 2p+1} ----
  // lanes lm<8: slot 2p (tile wv+8p); lanes lm>=8: slot 2p+1 (tile wv+8p+4)
  bool il1P[2]; int dP[2];
  #pragma unroll
  for (int p = 0; p < 2; ++p) {
    const int ua = 4*(wv + 8*p) + lk;
    const int ub = 4*(wv + 8*p + 4) + lk;
    const int u  = (lm < 8) ? ua : ub;
    il1P[p] = (u < H1);
    dP[p]   = il1P[p] ? (38 + u) : (88 + (u - H1));
  }
  const bool hasC = w16 && (lk == 0) && (lm < 8);

  // ---- x staging: 304 f32/step over 256 threads ----
  const int e1x = tid + 256;
  const bool v1 = (tid < SB*I1 - 256);       // tid < 48
  const int s0 = tid / I1,  k0 = tid % I1;
  const int s1 = e1x / I1,  k1 = e1x % I1;
  const int gb0 = s0*TT*I1 + k0, gb1 = v1 ? (s1*TT*I1 + k1) : 0;
  const int lb0 = s0*XS + k0,    lb1 = v1 ? (s1*XS + k1) : 0;

  __syncthreads();              // zeros visible
  {                             // stage x(0)
    _Float16* b0 = &bufA[0][0][0];
    b0[lb0] = (_Float16)xblk[gb0];
    if (v1) b0[lb1] = (_Float16)xblk[gb1];
  }
  float xA0 = 0.f, xA1 = 0.f, xB0 = 0.f, xB1 = 0.f;
  xA0 = xblk[gb0 + I1];                     // prefetch x(1)
  if (v1) xA1 = xblk[gb1 + I1];
  __syncthreads();

  float cP0 = 0.f, cP1 = 0.f, cC = 0.f;

#define DENSE_UPD(AA, AB, CVAR, PIDX, T, NXT) do {                              \
    f32x4 accD;                                                                 \
    _Pragma("unroll")                                                           \
    for (int m = 0; m < 4; ++m)                                                 \
      accD[m] = (lm < 8) ? (AA)[m] : (AB)[m];   /* cols 8-15 dup 0-7 */         \
    const bool up = il1P[PIDX] ? ((T) < TT) : ((T) >= 1);                       \
    float ig = sigm(accD[0]), fg = sigm(accD[1]);                               \
    float gg = tanh_f(accD[2]), og = sigm(accD[3]);                             \
    if (up) {                                                                   \
      CVAR = fg*CVAR + ig*gg;                                                   \
      (NXT)[arow*XS + dP[PIDX]] = (_Float16)(og * tanh_f(CVAR));                \
    }                                                                           \
  } while (0)

#define STEP(T, XC0, XC1, XN0, XN1) do {                                        \
    _Float16* cur = &bufA[(T) & 1][0][0];                                       \
    _Float16* nxt = &bufA[((T) & 1) ^ 1][0][0];                                 \
    if ((T) + 2 < TT) {                                                         \
      const int go = ((T) + 2) * I1;                                            \
      XN0 = xblk[gb0 + go];                                                     \
      if (v1) XN1 = xblk[gb1 + go];                                             \
    }                                                                           \
    f16x8 a0 = *(const f16x8*)(cur + arow*XS +      lk*8);                      \
    f16x8 a1 = *(const f16x8*)(cur + arow*XS + 32 + lk*8);                      \
    f16x8 a2 = *(const f16x8*)(cur + arow*XS + 64 + lk*8);                      \
    f16x8 a3 = *(const f16x8*)(cur + arow*XS + 96 + lk*8);                      \
    f32x4 A0 = (f32x4){sb[0][0], sb[0][1], sb[0][2], sb[0][3]};                 \
    A0 = MF(W0[0], a0, A0); A0 = MF(W0[1], a1, A0); A0 = MF(W0[2], a2, A0);     \
    f32x4 A1 = (f32x4){sb[1][0], sb[1][1], sb[1][2], sb[1][3]};                 \
    A1 = MF(W1[0], a0, A1); A1 = MF(W1[1], a1, A1); A1 = MF(W1[2], a2, A1);     \
    DENSE_UPD(A0, A1, cP0, 0, T, nxt);                                          \
    f32x4 A2 = (f32x4){sb[2][0], sb[2][1], sb[2][2], sb[2][3]};                 \
    A2 = MF(W2[0], a0, A2); A2 = MF(W2[1], a1, A2); A2 = MF(W2[2], a2, A2);     \
    f32x4 A3 = (f32x4){sb[3][0], sb[3][1], sb[3][2], sb[3][3]};                 \
    A3 = MF(W3[0], a0, A3); A3 = MF(W3[1], a1, A3);                             \
    A3 = MF(W3[2], a2, A3); A3 = MF(W3[3], a3, A3);                             \
    DENSE_UPD(A2, A3, cP1, 1, T, nxt);                                          \
    if (w16) {                                                                  \
      f32x4 acc = (f32x4){sbC[0], sbC[1], sbC[2], sbC[3]};                      \
      acc = MF(W16[0], a1, acc); acc = MF(W16[1], a2, acc);                     \
      acc = MF(W16[2], a3, acc);                                                \
      float ig = sigm(acc[0]), fg = sigm(acc[1]);                               \
      float gg = tanh_f(acc[2]), og = sigm(acc[3]);                             \
      if (hasC && (T) >= 1) {                                                   \
        cC = fg*cC + ig*gg;                                                     \
        nxt[arow*XS + 102] = (_Float16)(og * tanh_f(cC));                       \
      }                                                                         \
    }                                                                           \
    if ((T) + 1 < TT) {                                                         \
      nxt[lb0] = (_Float16)XC0;                                                 \
      if (v1) nxt[lb1] = (_Float16)XC1;                                         \
    }                                                                           \
    __syncthreads();                                                            \
  } while (0)

  int t = 0;
  for (;;) {
    STEP(t, xA0, xA1, xB0, xB1);
    if (++t > TT) break;
    STEP(t, xB0, xB1, xA0, xA1);
    if (++t > TT) break;
  }
#undef STEP
#undef DENSE_UPD

  // ---- FC on h2(255) (bufA[1], cols 88..102) ----
  if (tid < SB*NC) {
    int s = tid / NC, n = tid % NC;
    float acc = b_fc[n];
    #pragma unroll
    for (int u = 0; u < H2; ++u)
      acc += (float)bufA[1][s][88 + u] * w_fc[n*H2 + u];
    out[((size_t)blk*SB + s)*NC + n] = acc;
  }
}

extern "C" void kernel_launch(void* const* d_in, const int* in_sizes, int n_in,
                              void* d_out, int out_size, void* d_ws, size_t ws_size,
                              hipStream_t stream) {
  (void)n_in; (void)d_ws; (void)ws_size; (void)out_size;
  const float* x     = (const float*)d_in[0];
  const float* w_ih1 = (const float*)d_in[1];
  const float* w_hh1 = (const float*)d_in[2];
  const float* b_ih1 = (const float*)d_in[3];
  const float* b_hh1 = (const float*)d_in[4];
  const float* w_ih2 = (const float*)d_in[5];
  const float* w_hh2 = (const float*)d_in[6];
  const float* b_ih2 = (const float*)d_in[7];
  const float* b_hh2 = (const float*)d_in[8];
  const float* w_fc  = (const float*)d_in[9];
  const float* b_fc  = (const float*)d_in[10];
  float* out = (float*)d_out;

  const int B = in_sizes[0] / (TT * I1);   // 4096
  dim3 grid(B / SB), block(NTH);
  lstm2_fused<<<grid, block, 0, stream>>>(x, w_ih1, w_hh1, b_ih1, b_hh1,
                                          w_ih2, w_hh2, b_ih2, b_hh2,
                                          w_fc, b_fc, out);
}